// Round 10
// baseline (845.727 us; speedup 1.0000x reference)
//
#include <hip/hip_runtime.h>
#include <math.h>

#define NLVL  16
#define TSZ   (1u << 19)
#define TMASK (TSZ - 1u)

struct ResArr { int m1[NLVL * 4]; };  // per level, per dim: res-1

typedef short  short8  __attribute__((ext_vector_type(8)));
typedef float  float4v __attribute__((ext_vector_type(4)));

static __device__ __forceinline__ unsigned short f2bf(float f) {
    unsigned u = __float_as_uint(f);
    return (unsigned short)((u + 0x7fffu + ((u >> 16) & 1u)) >> 16);  // RNE
}

// ---------------------------------------------------------------------------
// Encode: round-9 kernel (669 us total, ~98% of the 1-req/cy/L2-channel
// service roofline; mixed 16B-pair/8B gathers). Now launched as 4 dispatches
// of 4 levels each — identical per-point code (bit-exact), but each dispatch
// ~167 us so the MLP becomes visible in rocprof top-5.
// ---------------------------------------------------------------------------
__global__ __launch_bounds__(256, 4)
void ingp_encode(const float4* __restrict__ x,
                 const float2* __restrict__ table,
                 unsigned*     __restrict__ featbf,  // [NLVL][N] bf16 pairs
                 int N, int chunksPerLevel, int levelBase, ResArr res)
{
    const int lg    = blockIdx.x / chunksPerLevel;
    const int chunk = blockIdx.x - lg * chunksPerLevel;
    const int l     = levelBase + lg;
    const int n     = chunk * 256 + threadIdx.x;
    if (n >= N) return;

    const float4 xv = x[n];
    const float px[4] = {xv.x, xv.y, xv.z, xv.w};

    int   bi[4];
    float fr[4], om[4];
    #pragma unroll
    for (int d = 0; d < 4; ++d) {
        const int r = res.m1[l * 4 + d];       // wave-uniform -> scalar
        const float pos = px[d] * (float)r;
        const float fb  = floorf(pos);
        fr[d] = pos - fb;
        om[d] = 1.0f - fr[d];
        bi[d] = (int)fb;
    }
    const float2* tl  = table + (size_t)l * TSZ;
    const float4* tl4 = (const float4*)tl;

    unsigned hrest[8];
    #pragma unroll
    for (int p = 0; p < 8; ++p) {
        const int c1 = bi[1] + ( p       & 1);
        const int c2 = bi[2] + ((p >> 1) & 1);
        const int c3 = bi[3] + ((p >> 2) & 1);
        hrest[p] = ((unsigned)c1 * 2654435761u)
                 ^ ((unsigned)c2 * 805459861u)
                 ^ ((unsigned)c3 * 3674653429u);
    }

    float2 fv[16];   // fv[2p] = dim0-offset 0, fv[2p+1] = dim0-offset 1
    if ((bi[0] & 1) == 0) {
        #pragma unroll
        for (int p = 0; p < 8; ++p) {
            const unsigned h = ((unsigned)bi[0] ^ hrest[p]) & TMASK;
            const float4 q = tl4[h >> 1];
            const bool odd = (h & 1);
            fv[2 * p]     = odd ? make_float2(q.z, q.w) : make_float2(q.x, q.y);
            fv[2 * p + 1] = odd ? make_float2(q.x, q.y) : make_float2(q.z, q.w);
        }
    } else {
        #pragma unroll
        for (int p = 0; p < 8; ++p) {
            const unsigned hA = ((unsigned)bi[0]       ^ hrest[p]) & TMASK;
            const unsigned hB = ((unsigned)(bi[0] + 1) ^ hrest[p]) & TMASK;
            fv[2 * p]     = tl[hA];
            fv[2 * p + 1] = tl[hB];
        }
    }

    float wt[16];
    #pragma unroll
    for (int c = 0; c < 16; ++c) {
        float w = ( c       & 1) ? fr[0] : om[0];
        w      *= ((c >> 1) & 1) ? fr[1] : om[1];
        w      *= ((c >> 2) & 1) ? fr[2] : om[2];
        w      *= ((c >> 3) & 1) ? fr[3] : om[3];
        wt[c] = w;
    }

    float a0 = 0.0f, a1 = 0.0f;
    #pragma unroll
    for (int c = 0; c < 16; ++c) {           // same order as reference einsum
        a0 = fmaf(wt[c], fv[c].x, a0);
        a1 = fmaf(wt[c], fv[c].y, a1);
    }
    featbf[(size_t)l * N + n] = (unsigned)f2bf(a0) | ((unsigned)f2bf(a1) << 16);
}

// ---------------------------------------------------------------------------
// MFMA MLP — round-8 structure + SOFTWARE-PIPELINED feat loads: tile t+1's
// 4 feat dwords are issued before tile t's MFMA/LDS chain, hiding the
// ~900-cy L2/HBM miss latency (leading theory for the unexplained 169 us).
// Everything else (fragments, LDS transform, FMA order) byte-identical.
// ---------------------------------------------------------------------------
__global__ __launch_bounds__(256, 2)
void ingp_mlp_mfma(const unsigned* __restrict__ featbf,  // [NLVL][N]
                   const float*    __restrict__ w0,
                   const float*    __restrict__ w1,
                   const float*    __restrict__ w2,
                   const float*    __restrict__ wout,
                   const float*    __restrict__ bout,
                   float*          __restrict__ out,
                   int N, int tilesPerWave)
{
    __shared__ char lds_raw[4 * 16 * 144];
    const int tid  = threadIdx.x;
    const int wave = tid >> 6;
    const int lane = tid & 63;
    const int q    = lane >> 4;     // quad: K-chunk selector
    const int nn   = lane & 15;     // neuron / point within tile
    char* hbase = lds_raw + wave * (16 * 144);

    short8 w0f[4];
    #pragma unroll
    for (int t = 0; t < 4; ++t) {
        const float* wr = w0 + (t * 16 + nn) * 32 + q * 8;
        #pragma unroll
        for (int e = 0; e < 8; ++e) w0f[t][e] = (short)f2bf(wr[e]);
    }
    short8 w1f[2][4], w2f[2][4];
    #pragma unroll
    for (int s = 0; s < 2; ++s) {
        #pragma unroll
        for (int t = 0; t < 4; ++t) {
            const float* wr1 = w1 + (t * 16 + nn) * 64 + s * 32 + q * 8;
            const float* wr2 = w2 + (t * 16 + nn) * 64 + s * 32 + q * 8;
            #pragma unroll
            for (int e = 0; e < 8; ++e) {
                w1f[s][t][e] = (short)f2bf(wr1[e]);
                w2f[s][t][e] = (short)f2bf(wr2[e]);
            }
        }
    }
    short8 wof[2];
    #pragma unroll
    for (int s = 0; s < 2; ++s) {
        #pragma unroll
        for (int e = 0; e < 8; ++e) {
            wof[s][e] = (nn < 3) ? (short)f2bf(wout[nn * 64 + s * 32 + q * 8 + e])
                                 : (short)0;
        }
    }
    const float bias = (nn < 3) ? bout[nn] : 0.0f;

    const int waveId = blockIdx.x * 4 + wave;

    // ---- prologue: prefetch tile 0's feats ----
    unsigned uf[4];
    {
        const int p0 = (waveId * tilesPerWave) * 16;
        const int p  = (p0 < N) ? (p0 + nn) : 0;
        #pragma unroll
        for (int v = 0; v < 4; ++v)
            uf[v] = featbf[(size_t)(q * 4 + v) * N + p];
    }

    for (int it = 0; it < tilesPerWave; ++it) {
        const int p0 = (waveId * tilesPerWave + it) * 16;
        if (p0 >= N) break;

        // A-frag for this tile from the prefetched dwords
        short8 a0;
        #pragma unroll
        for (int v = 0; v < 4; ++v) {
            const unsigned u = uf[v];
            a0[2 * v]     = (short)(u & 0xffffu);
            a0[2 * v + 1] = (short)(u >> 16);
        }

        // prefetch NEXT tile's feats (issued before the MFMA/LDS chain)
        {
            const int p0n = p0 + 16;
            const bool more = (it + 1 < tilesPerWave) && (p0n < N);
            const int pn = more ? (p0n + nn) : 0;
            #pragma unroll
            for (int v = 0; v < 4; ++v)
                uf[v] = featbf[(size_t)(q * 4 + v) * N + pn];
        }

        float4v acc0[4];
        #pragma unroll
        for (int t = 0; t < 4; ++t) {
            acc0[t] = (float4v){0.f, 0.f, 0.f, 0.f};
            acc0[t] = __builtin_amdgcn_mfma_f32_16x16x32_bf16(a0, w0f[t], acc0[t], 0, 0, 0);
        }
        #pragma unroll
        for (int t = 0; t < 4; ++t)
            #pragma unroll
            for (int r = 0; r < 4; ++r)
                *(unsigned short*)(hbase + (q * 4 + r) * 144 + (t * 16 + nn) * 2) =
                    f2bf(fmaxf(acc0[t][r], 0.0f));

        short8 a1[2];
        #pragma unroll
        for (int s = 0; s < 2; ++s)
            a1[s] = *(const short8*)(hbase + nn * 144 + s * 64 + q * 16);
        float4v acc1[4];
        #pragma unroll
        for (int t = 0; t < 4; ++t) {
            acc1[t] = (float4v){0.f, 0.f, 0.f, 0.f};
            #pragma unroll
            for (int s = 0; s < 2; ++s)
                acc1[t] = __builtin_amdgcn_mfma_f32_16x16x32_bf16(a1[s], w1f[s][t], acc1[t], 0, 0, 0);
        }
        #pragma unroll
        for (int t = 0; t < 4; ++t)
            #pragma unroll
            for (int r = 0; r < 4; ++r)
                *(unsigned short*)(hbase + (q * 4 + r) * 144 + (t * 16 + nn) * 2) =
                    f2bf(fmaxf(acc1[t][r], 0.0f));

        short8 a2[2];
        #pragma unroll
        for (int s = 0; s < 2; ++s)
            a2[s] = *(const short8*)(hbase + nn * 144 + s * 64 + q * 16);
        float4v acc2[4];
        #pragma unroll
        for (int t = 0; t < 4; ++t) {
            acc2[t] = (float4v){0.f, 0.f, 0.f, 0.f};
            #pragma unroll
            for (int s = 0; s < 2; ++s)
                acc2[t] = __builtin_amdgcn_mfma_f32_16x16x32_bf16(a2[s], w2f[s][t], acc2[t], 0, 0, 0);
        }
        #pragma unroll
        for (int t = 0; t < 4; ++t)
            #pragma unroll
            for (int r = 0; r < 4; ++r)
                *(unsigned short*)(hbase + (q * 4 + r) * 144 + (t * 16 + nn) * 2) =
                    f2bf(fmaxf(acc2[t][r], 0.0f));

        short8 a3[2];
        #pragma unroll
        for (int s = 0; s < 2; ++s)
            a3[s] = *(const short8*)(hbase + nn * 144 + s * 64 + q * 16);
        float4v oc = (float4v){0.f, 0.f, 0.f, 0.f};
        #pragma unroll
        for (int s = 0; s < 2; ++s)
            oc = __builtin_amdgcn_mfma_f32_16x16x32_bf16(a3[s], wof[s], oc, 0, 0, 0);

        if (nn < 3) {
            #pragma unroll
            for (int r = 0; r < 4; ++r) {
                const int pt = p0 + q * 4 + r;
                if (pt < N) out[pt * 3 + nn] = oc[r] + bias;
            }
        }
    }
}

// ---------------------------------------------------------------------------
// Fallback: round-2 fused kernel (used only if ws is too small for features).
// ---------------------------------------------------------------------------
__global__ __launch_bounds__(256, 2)
void ingp_fused(const float4* __restrict__ x,
                const float2* __restrict__ table,
                const float*  __restrict__ w0,
                const float*  __restrict__ w1,
                const float*  __restrict__ w2,
                const float*  __restrict__ wout,
                const float*  __restrict__ bout,
                float*        __restrict__ out,
                int N, ResArr res)
{
    const int n = blockIdx.x * blockDim.x + threadIdx.x;
    if (n >= N) return;

    const float4 xv = x[n];
    const float px[4] = {xv.x, xv.y, xv.z, xv.w};

    float h1[64];
    #pragma unroll
    for (int j = 0; j < 64; ++j) h1[j] = 0.0f;

    float a0p = 0.0f, a1p = 0.0f;

    #pragma unroll 1
    for (int l = 0; l < NLVL; ++l) {
        int   rm[4], bi[4];
        float fr[4], om[4];
        #pragma unroll
        for (int d = 0; d < 4; ++d) {
            const int r = res.m1[l * 4 + d];
            rm[d] = r;
            const float pos = px[d] * (float)r;
            const float fb  = floorf(pos);
            fr[d] = pos - fb;
            om[d] = 1.0f - fr[d];
            bi[d] = (int)fb;
        }
        const float2* tl = table + (size_t)l * TSZ;

        float2 fv[16];
        float  wt[16];
        #pragma unroll
        for (int c = 0; c < 16; ++c) {
            int c0 = bi[0] + ( c       & 1);
            int c1 = bi[1] + ((c >> 1) & 1);
            int c2 = bi[2] + ((c >> 2) & 1);
            int c3 = bi[3] + ((c >> 3) & 1);
            c0 = min(max(c0, 0), rm[0]);
            c1 = min(max(c1, 0), rm[1]);
            c2 = min(max(c2, 0), rm[2]);
            c3 = min(max(c3, 0), rm[3]);
            const unsigned hh = (unsigned)c0
                              ^ ((unsigned)c1 * 2654435761u)
                              ^ ((unsigned)c2 * 805459861u)
                              ^ ((unsigned)c3 * 3674653429u);
            fv[c] = tl[hh & TMASK];
            float w = ( c       & 1) ? fr[0] : om[0];
            w      *= ((c >> 1) & 1) ? fr[1] : om[1];
            w      *= ((c >> 2) & 1) ? fr[2] : om[2];
            w      *= ((c >> 3) & 1) ? fr[3] : om[3];
            wt[c] = w;
        }
        {
            const int lp = (l == 0) ? 0 : (l - 1);
            const float* w0c = w0 + 2 * lp;
            #pragma unroll
            for (int j = 0; j < 64; ++j)
                h1[j] = fmaf(w0c[j * 32], a0p, fmaf(w0c[j * 32 + 1], a1p, h1[j]));
        }
        float a0 = 0.0f, a1 = 0.0f;
        #pragma unroll
        for (int c = 0; c < 16; ++c) {
            a0 = fmaf(wt[c], fv[c].x, a0);
            a1 = fmaf(wt[c], fv[c].y, a1);
        }
        a0p = a0; a1p = a1;
    }
    {
        const float* w0c = w0 + 2 * (NLVL - 1);
        #pragma unroll
        for (int j = 0; j < 64; ++j)
            h1[j] = fmaf(w0c[j * 32], a0p, fmaf(w0c[j * 32 + 1], a1p, h1[j]));
    }
    #pragma unroll
    for (int j = 0; j < 64; ++j) h1[j] = fmaxf(h1[j], 0.0f);

    float h2[64];
    #pragma unroll
    for (int j = 0; j < 64; ++j) {
        float acc = 0.0f;
        const float* wr = w1 + j * 64;
        #pragma unroll
        for (int i = 0; i < 64; ++i) acc = fmaf(wr[i], h1[i], acc);
        h2[j] = fmaxf(acc, 0.0f);
    }
    float h3[64];
    #pragma unroll
    for (int j = 0; j < 64; ++j) {
        float acc = 0.0f;
        const float* wr = w2 + j * 64;
        #pragma unroll
        for (int i = 0; i < 64; ++i) acc = fmaf(wr[i], h2[i], acc);
        h3[j] = fmaxf(acc, 0.0f);
    }
    float o[3];
    #pragma unroll
    for (int k = 0; k < 3; ++k) {
        float acc = bout[k];
        const float* wr = wout + k * 64;
        #pragma unroll
        for (int i = 0; i < 64; ++i) acc = fmaf(wr[i], h3[i], acc);
        o[k] = acc;
    }
    out[n * 3 + 0] = o[0];
    out[n * 3 + 1] = o[1];
    out[n * 3 + 2] = o[2];
}

extern "C" void kernel_launch(void* const* d_in, const int* in_sizes, int n_in,
                              void* d_out, int out_size, void* d_ws, size_t ws_size,
                              hipStream_t stream) {
    (void)n_in; (void)out_size;

    const float* x     = (const float*)d_in[0];
    const float* table = (const float*)d_in[1];
    const float* w0    = (const float*)d_in[2];
    const float* w1    = (const float*)d_in[3];
    const float* w2    = (const float*)d_in[4];
    const float* wout  = (const float*)d_in[5];
    const float* bout  = (const float*)d_in[6];
    float* out = (float*)d_out;

    const int N = in_sizes[0] / 4;

    // Replicate numpy's float64 resolution computation bit-for-bit (same
    // glibc pow). Levels 5/10/15 of dim 3 sit on exact integer boundaries
    // (8^(5/15)==2), so floor() must see the same double as numpy produced.
    ResArr res;
    for (int d = 0; d < 4; ++d) {
        const double minr = 16.0;
        const double maxr = (d == 3) ? 128.0 : 256.0;
        const double growth = pow(maxr / minr, 1.0 / (double)(NLVL - 1));
        for (int l = 0; l < NLVL; ++l) {
            const int r = (int)floor(minr * pow(growth, (double)l));
            res.m1[l * 4 + d] = r - 1;
        }
    }

    const size_t featBytes = (size_t)NLVL * (size_t)N * sizeof(unsigned);
    const int chunksPerLevel = (N + 255) / 256;

    if (ws_size >= featBytes) {
        unsigned* featbf = (unsigned*)d_ws;
        // 4 dispatches x 4 levels: identical per-point work, makes the MLP
        // visible in rocprof's top-5 dispatches.
        for (int g = 0; g < 4; ++g) {
            hipLaunchKernelGGL(ingp_encode, dim3(4 * chunksPerLevel), dim3(256),
                               0, stream, (const float4*)x, (const float2*)table,
                               featbf, N, chunksPerLevel, g * 4, res);
        }

        const int tilesPerWave = 8;
        const int tiles  = (N + 15) / 16;
        const int waves  = (tiles + tilesPerWave - 1) / tilesPerWave;
        const int blocks = (waves + 3) / 4;
        hipLaunchKernelGGL(ingp_mlp_mfma, dim3(blocks), dim3(256), 0, stream,
                           featbf, w0, w1, w2, wout, bout, out, N, tilesPerWave);
    } else {
        hipLaunchKernelGGL(ingp_fused, dim3((N + 255) / 256), dim3(256), 0, stream,
                           (const float4*)x, (const float2*)table,
                           w0, w1, w2, wout, bout, out, N, res);
    }
}

// Round 11
// 836.445 us; speedup vs baseline: 1.0111x; 1.0111x over previous
//
#include <hip/hip_runtime.h>
#include <math.h>

#define NLVL  16
#define TSZ   (1u << 19)
#define TMASK (TSZ - 1u)

struct ResArr { int m1[NLVL * 4]; };  // per level, per dim: res-1

typedef short  short8  __attribute__((ext_vector_type(8)));
typedef float  float4v __attribute__((ext_vector_type(4)));

static __device__ __forceinline__ unsigned short f2bf(float f) {
    unsigned u = __float_as_uint(f);
    return (unsigned short)((u + 0x7fffu + ((u >> 16) & 1u)) >> 16);  // RNE
}

// ---------------------------------------------------------------------------
// Encode: round-9 kernel, SINGLE dispatch (669 us, ~98% of the 1-req/cy per
// L2-channel service roofline; mixed 16B-pair/8B gathers via the PRIMES[0]==1
// corner-pair trick). Round-10's 4-way split cost +47 us of dispatch overhead
// with no information we still need — reverted.
// ---------------------------------------------------------------------------
__global__ __launch_bounds__(256, 4)
void ingp_encode(const float4* __restrict__ x,
                 const float2* __restrict__ table,
                 unsigned*     __restrict__ featbf,  // [NLVL][N] bf16 pairs
                 int N, int chunksPerLevel, ResArr res)
{
    const int l     = blockIdx.x / chunksPerLevel;
    const int chunk = blockIdx.x - l * chunksPerLevel;
    const int n     = chunk * 256 + threadIdx.x;
    if (n >= N) return;

    const float4 xv = x[n];
    const float px[4] = {xv.x, xv.y, xv.z, xv.w};

    int   bi[4];
    float fr[4], om[4];
    #pragma unroll
    for (int d = 0; d < 4; ++d) {
        const int r = res.m1[l * 4 + d];       // wave-uniform -> scalar
        const float pos = px[d] * (float)r;
        const float fb  = floorf(pos);
        fr[d] = pos - fb;
        om[d] = 1.0f - fr[d];
        bi[d] = (int)fb;
    }
    const float2* tl  = table + (size_t)l * TSZ;
    const float4* tl4 = (const float4*)tl;

    unsigned hrest[8];
    #pragma unroll
    for (int p = 0; p < 8; ++p) {
        const int c1 = bi[1] + ( p       & 1);
        const int c2 = bi[2] + ((p >> 1) & 1);
        const int c3 = bi[3] + ((p >> 2) & 1);
        hrest[p] = ((unsigned)c1 * 2654435761u)
                 ^ ((unsigned)c2 * 805459861u)
                 ^ ((unsigned)c3 * 3674653429u);
    }

    float2 fv[16];   // fv[2p] = dim0-offset 0, fv[2p+1] = dim0-offset 1
    if ((bi[0] & 1) == 0) {
        #pragma unroll
        for (int p = 0; p < 8; ++p) {
            const unsigned h = ((unsigned)bi[0] ^ hrest[p]) & TMASK;
            const float4 q = tl4[h >> 1];
            const bool odd = (h & 1);
            fv[2 * p]     = odd ? make_float2(q.z, q.w) : make_float2(q.x, q.y);
            fv[2 * p + 1] = odd ? make_float2(q.x, q.y) : make_float2(q.z, q.w);
        }
    } else {
        #pragma unroll
        for (int p = 0; p < 8; ++p) {
            const unsigned hA = ((unsigned)bi[0]       ^ hrest[p]) & TMASK;
            const unsigned hB = ((unsigned)(bi[0] + 1) ^ hrest[p]) & TMASK;
            fv[2 * p]     = tl[hA];
            fv[2 * p + 1] = tl[hB];
        }
    }

    float wt[16];
    #pragma unroll
    for (int c = 0; c < 16; ++c) {
        float w = ( c       & 1) ? fr[0] : om[0];
        w      *= ((c >> 1) & 1) ? fr[1] : om[1];
        w      *= ((c >> 2) & 1) ? fr[2] : om[2];
        w      *= ((c >> 3) & 1) ? fr[3] : om[3];
        wt[c] = w;
    }

    float a0 = 0.0f, a1 = 0.0f;
    #pragma unroll
    for (int c = 0; c < 16; ++c) {           // same order as reference einsum
        a0 = fmaf(wt[c], fv[c].x, a0);
        a1 = fmaf(wt[c], fv[c].y, a1);
    }
    featbf[(size_t)l * N + n] = (unsigned)f2bf(a0) | ((unsigned)f2bf(a1) << 16);
}

// ---------------------------------------------------------------------------
// MFMA MLP — round-8 structure + DEPTH-2 prefetch ring (A/B buffers, loop
// unrolled x2 so all register arrays stay constant-indexed). Measured: no
// prefetch 165 us -> depth-1 120 us; the feat-load miss-latency chain is the
// limiter, depth-2 covers ~900 cy fully. Fragments/LDS/FMA order unchanged.
// ---------------------------------------------------------------------------
#define TILE_BODY(P0, A0)                                                     \
{                                                                             \
    float4v acc0[4];                                                          \
    _Pragma("unroll")                                                         \
    for (int t = 0; t < 4; ++t) {                                             \
        acc0[t] = (float4v){0.f, 0.f, 0.f, 0.f};                              \
        acc0[t] = __builtin_amdgcn_mfma_f32_16x16x32_bf16(A0, w0f[t], acc0[t], 0, 0, 0); \
    }                                                                         \
    _Pragma("unroll")                                                         \
    for (int t = 0; t < 4; ++t)                                               \
        _Pragma("unroll")                                                     \
        for (int r = 0; r < 4; ++r)                                           \
            *(unsigned short*)(hbase + (q * 4 + r) * 144 + (t * 16 + nn) * 2) = \
                f2bf(fmaxf(acc0[t][r], 0.0f));                                \
    short8 a1[2];                                                             \
    _Pragma("unroll")                                                         \
    for (int s = 0; s < 2; ++s)                                               \
        a1[s] = *(const short8*)(hbase + nn * 144 + s * 64 + q * 16);         \
    float4v acc1[4];                                                          \
    _Pragma("unroll")                                                         \
    for (int t = 0; t < 4; ++t) {                                             \
        acc1[t] = (float4v){0.f, 0.f, 0.f, 0.f};                              \
        _Pragma("unroll")                                                     \
        for (int s = 0; s < 2; ++s)                                           \
            acc1[t] = __builtin_amdgcn_mfma_f32_16x16x32_bf16(a1[s], w1f[s][t], acc1[t], 0, 0, 0); \
    }                                                                         \
    _Pragma("unroll")                                                         \
    for (int t = 0; t < 4; ++t)                                               \
        _Pragma("unroll")                                                     \
        for (int r = 0; r < 4; ++r)                                           \
            *(unsigned short*)(hbase + (q * 4 + r) * 144 + (t * 16 + nn) * 2) = \
                f2bf(fmaxf(acc1[t][r], 0.0f));                                \
    short8 a2[2];                                                             \
    _Pragma("unroll")                                                         \
    for (int s = 0; s < 2; ++s)                                               \
        a2[s] = *(const short8*)(hbase + nn * 144 + s * 64 + q * 16);         \
    float4v acc2[4];                                                          \
    _Pragma("unroll")                                                         \
    for (int t = 0; t < 4; ++t) {                                             \
        acc2[t] = (float4v){0.f, 0.f, 0.f, 0.f};                              \
        _Pragma("unroll")                                                     \
        for (int s = 0; s < 2; ++s)                                           \
            acc2[t] = __builtin_amdgcn_mfma_f32_16x16x32_bf16(a2[s], w2f[s][t], acc2[t], 0, 0, 0); \
    }                                                                         \
    _Pragma("unroll")                                                         \
    for (int t = 0; t < 4; ++t)                                               \
        _Pragma("unroll")                                                     \
        for (int r = 0; r < 4; ++r)                                           \
            *(unsigned short*)(hbase + (q * 4 + r) * 144 + (t * 16 + nn) * 2) = \
                f2bf(fmaxf(acc2[t][r], 0.0f));                                \
    short8 a3[2];                                                             \
    _Pragma("unroll")                                                         \
    for (int s = 0; s < 2; ++s)                                               \
        a3[s] = *(const short8*)(hbase + nn * 144 + s * 64 + q * 16);         \
    float4v oc = (float4v){0.f, 0.f, 0.f, 0.f};                               \
    _Pragma("unroll")                                                         \
    for (int s = 0; s < 2; ++s)                                               \
        oc = __builtin_amdgcn_mfma_f32_16x16x32_bf16(a3[s], wof[s], oc, 0, 0, 0); \
    if (nn < 3) {                                                             \
        _Pragma("unroll")                                                     \
        for (int r = 0; r < 4; ++r) {                                         \
            const int pt = (P0) + q * 4 + r;                                  \
            if (pt < N) out[pt * 3 + nn] = oc[r] + bias;                      \
        }                                                                     \
    }                                                                         \
}

__global__ __launch_bounds__(256, 2)
void ingp_mlp_mfma(const unsigned* __restrict__ featbf,  // [NLVL][N]
                   const float*    __restrict__ w0,
                   const float*    __restrict__ w1,
                   const float*    __restrict__ w2,
                   const float*    __restrict__ wout,
                   const float*    __restrict__ bout,
                   float*          __restrict__ out,
                   int N, int tilesPerWave)
{
    __shared__ char lds_raw[4 * 16 * 144];
    const int tid  = threadIdx.x;
    const int wave = tid >> 6;
    const int lane = tid & 63;
    const int q    = lane >> 4;     // quad: K-chunk selector
    const int nn   = lane & 15;     // neuron / point within tile
    char* hbase = lds_raw + wave * (16 * 144);

    short8 w0f[4];
    #pragma unroll
    for (int t = 0; t < 4; ++t) {
        const float* wr = w0 + (t * 16 + nn) * 32 + q * 8;
        #pragma unroll
        for (int e = 0; e < 8; ++e) w0f[t][e] = (short)f2bf(wr[e]);
    }
    short8 w1f[2][4], w2f[2][4];
    #pragma unroll
    for (int s = 0; s < 2; ++s) {
        #pragma unroll
        for (int t = 0; t < 4; ++t) {
            const float* wr1 = w1 + (t * 16 + nn) * 64 + s * 32 + q * 8;
            const float* wr2 = w2 + (t * 16 + nn) * 64 + s * 32 + q * 8;
            #pragma unroll
            for (int e = 0; e < 8; ++e) {
                w1f[s][t][e] = (short)f2bf(wr1[e]);
                w2f[s][t][e] = (short)f2bf(wr2[e]);
            }
        }
    }
    short8 wof[2];
    #pragma unroll
    for (int s = 0; s < 2; ++s) {
        #pragma unroll
        for (int e = 0; e < 8; ++e) {
            wof[s][e] = (nn < 3) ? (short)f2bf(wout[nn * 64 + s * 32 + q * 8 + e])
                                 : (short)0;
        }
    }
    const float bias = (nn < 3) ? bout[nn] : 0.0f;

    const int waveId = blockIdx.x * 4 + wave;
    const int base   = waveId * tilesPerWave;

    // ---- prologue: prefetch tiles 0 and 1 ----
    unsigned ufA[4], ufB[4];
    {
        const int pA = (base * 16 < N) ? (base * 16 + nn) : 0;
        const int pB = ((base + 1) * 16 < N) ? ((base + 1) * 16 + nn) : 0;
        #pragma unroll
        for (int v = 0; v < 4; ++v) {
            ufA[v] = featbf[(size_t)(q * 4 + v) * N + pA];
            ufB[v] = featbf[(size_t)(q * 4 + v) * N + pB];
        }
    }

    for (int it = 0; it < tilesPerWave; it += 2) {
        const int p0A = (base + it) * 16;
        if (p0A >= N) break;

        // tile it: unpack A-frag, then immediately issue prefetch for it+2
        short8 a0A;
        #pragma unroll
        for (int v = 0; v < 4; ++v) {
            a0A[2 * v]     = (short)(ufA[v] & 0xffffu);
            a0A[2 * v + 1] = (short)(ufA[v] >> 16);
        }
        {
            const int p0n = (base + it + 2) * 16;
            const bool more = (it + 2 < tilesPerWave) && (p0n < N);
            const int pn = more ? (p0n + nn) : 0;
            #pragma unroll
            for (int v = 0; v < 4; ++v)
                ufA[v] = featbf[(size_t)(q * 4 + v) * N + pn];
        }
        TILE_BODY(p0A, a0A)

        // tile it+1
        const int p0B = (base + it + 1) * 16;
        if (p0B < N && it + 1 < tilesPerWave) {
            short8 a0B;
            #pragma unroll
            for (int v = 0; v < 4; ++v) {
                a0B[2 * v]     = (short)(ufB[v] & 0xffffu);
                a0B[2 * v + 1] = (short)(ufB[v] >> 16);
            }
            {
                const int p0n = (base + it + 3) * 16;
                const bool more = (it + 3 < tilesPerWave) && (p0n < N);
                const int pn = more ? (p0n + nn) : 0;
                #pragma unroll
                for (int v = 0; v < 4; ++v)
                    ufB[v] = featbf[(size_t)(q * 4 + v) * N + pn];
            }
            TILE_BODY(p0B, a0B)
        }
    }
}

// ---------------------------------------------------------------------------
// Fallback: round-2 fused kernel (used only if ws is too small for features).
// ---------------------------------------------------------------------------
__global__ __launch_bounds__(256, 2)
void ingp_fused(const float4* __restrict__ x,
                const float2* __restrict__ table,
                const float*  __restrict__ w0,
                const float*  __restrict__ w1,
                const float*  __restrict__ w2,
                const float*  __restrict__ wout,
                const float*  __restrict__ bout,
                float*        __restrict__ out,
                int N, ResArr res)
{
    const int n = blockIdx.x * blockDim.x + threadIdx.x;
    if (n >= N) return;

    const float4 xv = x[n];
    const float px[4] = {xv.x, xv.y, xv.z, xv.w};

    float h1[64];
    #pragma unroll
    for (int j = 0; j < 64; ++j) h1[j] = 0.0f;

    float a0p = 0.0f, a1p = 0.0f;

    #pragma unroll 1
    for (int l = 0; l < NLVL; ++l) {
        int   rm[4], bi[4];
        float fr[4], om[4];
        #pragma unroll
        for (int d = 0; d < 4; ++d) {
            const int r = res.m1[l * 4 + d];
            rm[d] = r;
            const float pos = px[d] * (float)r;
            const float fb  = floorf(pos);
            fr[d] = pos - fb;
            om[d] = 1.0f - fr[d];
            bi[d] = (int)fb;
        }
        const float2* tl = table + (size_t)l * TSZ;

        float2 fv[16];
        float  wt[16];
        #pragma unroll
        for (int c = 0; c < 16; ++c) {
            int c0 = bi[0] + ( c       & 1);
            int c1 = bi[1] + ((c >> 1) & 1);
            int c2 = bi[2] + ((c >> 2) & 1);
            int c3 = bi[3] + ((c >> 3) & 1);
            c0 = min(max(c0, 0), rm[0]);
            c1 = min(max(c1, 0), rm[1]);
            c2 = min(max(c2, 0), rm[2]);
            c3 = min(max(c3, 0), rm[3]);
            const unsigned hh = (unsigned)c0
                              ^ ((unsigned)c1 * 2654435761u)
                              ^ ((unsigned)c2 * 805459861u)
                              ^ ((unsigned)c3 * 3674653429u);
            fv[c] = tl[hh & TMASK];
            float w = ( c       & 1) ? fr[0] : om[0];
            w      *= ((c >> 1) & 1) ? fr[1] : om[1];
            w      *= ((c >> 2) & 1) ? fr[2] : om[2];
            w      *= ((c >> 3) & 1) ? fr[3] : om[3];
            wt[c] = w;
        }
        {
            const int lp = (l == 0) ? 0 : (l - 1);
            const float* w0c = w0 + 2 * lp;
            #pragma unroll
            for (int j = 0; j < 64; ++j)
                h1[j] = fmaf(w0c[j * 32], a0p, fmaf(w0c[j * 32 + 1], a1p, h1[j]));
        }
        float a0 = 0.0f, a1 = 0.0f;
        #pragma unroll
        for (int c = 0; c < 16; ++c) {
            a0 = fmaf(wt[c], fv[c].x, a0);
            a1 = fmaf(wt[c], fv[c].y, a1);
        }
        a0p = a0; a1p = a1;
    }
    {
        const float* w0c = w0 + 2 * (NLVL - 1);
        #pragma unroll
        for (int j = 0; j < 64; ++j)
            h1[j] = fmaf(w0c[j * 32], a0p, fmaf(w0c[j * 32 + 1], a1p, h1[j]));
    }
    #pragma unroll
    for (int j = 0; j < 64; ++j) h1[j] = fmaxf(h1[j], 0.0f);

    float h2[64];
    #pragma unroll
    for (int j = 0; j < 64; ++j) {
        float acc = 0.0f;
        const float* wr = w1 + j * 64;
        #pragma unroll
        for (int i = 0; i < 64; ++i) acc = fmaf(wr[i], h1[i], acc);
        h2[j] = fmaxf(acc, 0.0f);
    }
    float h3[64];
    #pragma unroll
    for (int j = 0; j < 64; ++j) {
        float acc = 0.0f;
        const float* wr = w2 + j * 64;
        #pragma unroll
        for (int i = 0; i < 64; ++i) acc = fmaf(wr[i], h2[i], acc);
        h3[j] = fmaxf(acc, 0.0f);
    }
    float o[3];
    #pragma unroll
    for (int k = 0; k < 3; ++k) {
        float acc = bout[k];
        const float* wr = wout + k * 64;
        #pragma unroll
        for (int i = 0; i < 64; ++i) acc = fmaf(wr[i], h3[i], acc);
        o[k] = acc;
    }
    out[n * 3 + 0] = o[0];
    out[n * 3 + 1] = o[1];
    out[n * 3 + 2] = o[2];
}

extern "C" void kernel_launch(void* const* d_in, const int* in_sizes, int n_in,
                              void* d_out, int out_size, void* d_ws, size_t ws_size,
                              hipStream_t stream) {
    (void)n_in; (void)out_size;

    const float* x     = (const float*)d_in[0];
    const float* table = (const float*)d_in[1];
    const float* w0    = (const float*)d_in[2];
    const float* w1    = (const float*)d_in[3];
    const float* w2    = (const float*)d_in[4];
    const float* wout  = (const float*)d_in[5];
    const float* bout  = (const float*)d_in[6];
    float* out = (float*)d_out;

    const int N = in_sizes[0] / 4;

    // Replicate numpy's float64 resolution computation bit-for-bit (same
    // glibc pow). Levels 5/10/15 of dim 3 sit on exact integer boundaries
    // (8^(5/15)==2), so floor() must see the same double as numpy produced.
    ResArr res;
    for (int d = 0; d < 4; ++d) {
        const double minr = 16.0;
        const double maxr = (d == 3) ? 128.0 : 256.0;
        const double growth = pow(maxr / minr, 1.0 / (double)(NLVL - 1));
        for (int l = 0; l < NLVL; ++l) {
            const int r = (int)floor(minr * pow(growth, (double)l));
            res.m1[l * 4 + d] = r - 1;
        }
    }

    const size_t featBytes = (size_t)NLVL * (size_t)N * sizeof(unsigned);
    const int chunksPerLevel = (N + 255) / 256;

    if (ws_size >= featBytes) {
        unsigned* featbf = (unsigned*)d_ws;
        hipLaunchKernelGGL(ingp_encode, dim3(NLVL * chunksPerLevel), dim3(256),
                           0, stream, (const float4*)x, (const float2*)table,
                           featbf, N, chunksPerLevel, res);

        const int tilesPerWave = 8;
        const int tiles  = (N + 15) / 16;
        const int waves  = (tiles + tilesPerWave - 1) / tilesPerWave;
        const int blocks = (waves + 3) / 4;
        hipLaunchKernelGGL(ingp_mlp_mfma, dim3(blocks), dim3(256), 0, stream,
                           featbf, w0, w1, w2, wout, bout, out, N, tilesPerWave);
    } else {
        hipLaunchKernelGGL(ingp_fused, dim3((N + 255) / 256), dim3(256), 0, stream,
                           (const float4*)x, (const float2*)table,
                           w0, w1, w2, wout, bout, out, N, res);
    }
}